// Round 17
// baseline (500.855 us; speedup 1.0000x reference)
//
#include <hip/hip_runtime.h>
#include <hip/hip_bf16.h>

#define NNODES 50000
#define NEDGES 800000
#define NG 64
#define D 64
#define D2 128
#define INDIM 39
#define EDIM 10
#define EPW 32             // edges per wave in k_agg (exact: 6250*4*32 = 800000)
#define BN_EPS 1e-5f
#define BN_BIAS 1e-4f
#define NSB ((NNODES + 255) / 256)   // 196 scan blocks

typedef __attribute__((ext_vector_type(8))) short bf16x8;
typedef __attribute__((ext_vector_type(4))) float f32x4;
typedef __attribute__((ext_vector_type(4))) unsigned uint32x4;

__device__ __forceinline__ float blo(unsigned u) {
    union { unsigned i; float f; } c; c.i = u << 16; return c.f;
}
__device__ __forceinline__ float bhi(unsigned u) {
    union { unsigned i; float f; } c; c.i = u & 0xffff0000u; return c.f;
}
__device__ __forceinline__ unsigned pk2(float a, float b) {
    __hip_bfloat16 ba = __float2bfloat16(a), bb = __float2bfloat16(b);
    return ((unsigned)*(unsigned short*)&bb << 16) | (unsigned)*(unsigned short*)&ba;
}

// ---------------- encoder: hin = x @ Wenc + benc (+ bf16 shadow, + zin init) ----------------
__global__ __launch_bounds__(256) void k_enc(const float* __restrict__ x,
                                             const float* __restrict__ Wenc,
                                             const float* __restrict__ benc,
                                             const float* __restrict__ eps,
                                             float* __restrict__ hin,
                                             __hip_bfloat16* __restrict__ hbf,
                                             float* __restrict__ zin) {
    __shared__ float sW[INDIM * D];
    for (int i = threadIdx.x; i < INDIM * D; i += 256) sW[i] = Wenc[i];
    __syncthreads();
    int wave = threadIdx.x >> 6, lane = threadIdx.x & 63;
    int row = blockIdx.x * 4 + wave;
    if (row >= NNODES) return;
    float xv = (lane < INDIM) ? x[row * INDIM + lane] : 0.f;
    float acc = benc[lane];
#pragma unroll
    for (int k = 0; k < INDIM; ++k) acc += __shfl(xv, k) * sW[k * D + lane];
    hin[row * D + lane] = acc;
    hbf[row * D + lane] = __float2bfloat16(acc);
    zin[row * D + lane] = (1.f + eps[0]) * acc;
}

// ---------------- CSR build ----------------
__global__ __launch_bounds__(256) void k_hist(const int* __restrict__ ei,
                                              int* __restrict__ deg) {
    int e = blockIdx.x * 256 + threadIdx.x;
    if (e < NEDGES) atomicAdd(&deg[ei[NEDGES + e]], 1);
}

__global__ __launch_bounds__(256) void k_scansum(const int* __restrict__ deg,
                                                 int* __restrict__ bsum) {
    int i = blockIdx.x * 256 + threadIdx.x;
    int v = (i < NNODES) ? deg[i] : 0;
#pragma unroll
    for (int o = 32; o; o >>= 1) v += __shfl_xor(v, o);
    __shared__ int ws[4];
    if ((threadIdx.x & 63) == 0) ws[threadIdx.x >> 6] = v;
    __syncthreads();
    if (threadIdx.x == 0) bsum[blockIdx.x] = ws[0] + ws[1] + ws[2] + ws[3];
}

__global__ __launch_bounds__(256) void k_scanbase(const int* __restrict__ bsum,
                                                  int* __restrict__ bbase) {
    __shared__ int s[256];
    int t = threadIdx.x;
    int v = (t < NSB) ? bsum[t] : 0;
    s[t] = v;
    __syncthreads();
    for (int o = 1; o < 256; o <<= 1) {
        int u = (t >= o) ? s[t - o] : 0;
        __syncthreads();
        s[t] += u;
        __syncthreads();
    }
    if (t < NSB) bbase[t] = s[t] - v;
}

__global__ __launch_bounds__(256) void k_scanwrite(const int* __restrict__ deg,
                                                   const int* __restrict__ bbase,
                                                   int* __restrict__ cursor) {
    __shared__ int s[256];
    int t = threadIdx.x;
    int i = blockIdx.x * 256 + t;
    int v = (i < NNODES) ? deg[i] : 0;
    s[t] = v;
    __syncthreads();
    for (int o = 1; o < 256; o <<= 1) {
        int u = (t >= o) ? s[t - o] : 0;
        __syncthreads();
        s[t] += u;
        __syncthreads();
    }
    int excl = bbase[blockIdx.x] + s[t] - v;
    if (i < NNODES) cursor[i] = excl;
}

// scatter fused 32B edge record {src, dst, 5 x bf16-pair} into CSR order.
// 1 edge/thread (max TLP); nontemporal stores to skip L2 write-allocate.
__global__ __launch_bounds__(256) void k_scatter(const int* __restrict__ ei,
                                                 const float* __restrict__ ea,
                                                 int* __restrict__ cursor,
                                                 unsigned* __restrict__ e32) {
    int e = blockIdx.x * 256 + threadIdx.x;
    if (e >= NEDGES) return;
    int s = ei[e], d = ei[NEDGES + e];
    int p = atomicAdd(&cursor[d], 1);
    unsigned u[5];
#pragma unroll
    for (int i = 0; i < 5; ++i)
        u[i] = pk2(ea[(size_t)e * EDIM + 2 * i], ea[(size_t)e * EDIM + 2 * i + 1]);
    uint32x4 lo = {(unsigned)s, (unsigned)d, u[0], u[1]};
    uint32x4 hi = {u[2], u[3], u[4], 0u};
    uint32x4* dst = (uint32x4*)(e32 + (size_t)p * 8);
    __builtin_nontemporal_store(lo, dst);
    __builtin_nontemporal_store(hi, dst + 1);
}

// ---------------- aggregate, edge-balanced, scalar edge stream ----------------
__global__ __launch_bounds__(256) void k_agg(const uint4* __restrict__ e32,
                                             const float* __restrict__ We,
                                             const float* __restrict__ be, int l,
                                             const __hip_bfloat16* __restrict__ hbf,
                                             float* __restrict__ zin) {
    int wid = __builtin_amdgcn_readfirstlane(threadIdx.x >> 6);
    int lane = threadIdx.x & 63;
    int j0 = (blockIdx.x * 4 + wid) * EPW;
    const float* Wl = We + l * EDIM * D;
    float w[EDIM];
#pragma unroll
    for (int k = 0; k < EDIM; ++k) w[k] = Wl[k * D + lane];
    float bias = be[l * D + lane];
    float acc = 0.f;
    const uint4* ep = e32 + (size_t)j0 * 2;
    int cur = (int)ep[0].y;
#define EMB(lo, hi, m)                                                                   \
    {                                                                                    \
        m = bias;                                                                        \
        m += blo(lo.z) * w[0] + bhi(lo.z) * w[1] + blo(lo.w) * w[2] + bhi(lo.w) * w[3];  \
        m += blo(hi.x) * w[4] + bhi(hi.x) * w[5] + blo(hi.y) * w[6] + bhi(hi.y) * w[7];  \
        m += blo(hi.z) * w[8] + bhi(hi.z) * w[9];                                        \
    }
#define STEP(dd, mm, hh)                                                                 \
    {                                                                                    \
        if (dd != cur) {                                                                 \
            atomicAdd(&zin[(size_t)cur * D + lane], acc);                                \
            acc = 0.f; cur = dd;                                                         \
        }                                                                                \
        acc += fmaxf(mm + hh, 0.f);                                                      \
    }
#pragma unroll 2
    for (int it = 0; it < EPW; it += 4) {
        const uint4* r = ep + it * 2;
        uint4 lo0 = r[0], hi0 = r[1];
        uint4 lo1 = r[2], hi1 = r[3];
        uint4 lo2 = r[4], hi2 = r[5];
        uint4 lo3 = r[6], hi3 = r[7];
        float hv0 = __bfloat162float(hbf[(size_t)lo0.x * D + lane]);
        float hv1 = __bfloat162float(hbf[(size_t)lo1.x * D + lane]);
        float hv2 = __bfloat162float(hbf[(size_t)lo2.x * D + lane]);
        float hv3 = __bfloat162float(hbf[(size_t)lo3.x * D + lane]);
        float m0, m1, m2, m3;
        EMB(lo0, hi0, m0) EMB(lo1, hi1, m1) EMB(lo2, hi2, m2) EMB(lo3, hi3, m3)
        STEP((int)lo0.y, m0, hv0)
        STEP((int)lo1.y, m1, hv1)
        STEP((int)lo2.y, m2, hv2)
        STEP((int)lo3.y, m3, hv3)
    }
#undef EMB
#undef STEP
    atomicAdd(&zin[(size_t)cur * D + lane], acc);
}

// ---------------- GEMM1 (MFMA): tbf = bf16(zin @ W1 + b1) (+ fp32 BN stats) ----------------
__global__ __launch_bounds__(256) void k_gemm1(const float* __restrict__ zin,
                                               const float* __restrict__ W1,
                                               const float* __restrict__ b1, int l,
                                               __hip_bfloat16* __restrict__ tbf,
                                               float* __restrict__ stats1) {
    __shared__ __hip_bfloat16 sWhi[D2][72];
    __shared__ __hip_bfloat16 sWlo[D2][72];
    __shared__ float sSum[D2], sSq[D2];
    const float* Wp = W1 + l * D * D2;
    for (int i = threadIdx.x; i < D * D2; i += 256) {
        int k = i >> 7, c = i & 127;
        float w = Wp[i];
        __hip_bfloat16 hi = __float2bfloat16(w);
        sWhi[c][k] = hi;
        sWlo[c][k] = __float2bfloat16(w - __bfloat162float(hi));
    }
    if (threadIdx.x < D2) { sSum[threadIdx.x] = 0.f; sSq[threadIdx.x] = 0.f; }
    __syncthreads();
    int wid = threadIdx.x >> 6, lane = threadIdx.x & 63;
    int lr = lane & 15, lg = lane >> 4;
    int rowA0 = blockIdx.x * 128 + wid * 32;
    bf16x8 afrag[2][2];
#pragma unroll
    for (int rt = 0; rt < 2; ++rt) {
        int row = rowA0 + rt * 16 + lr;
#pragma unroll
        for (int ks = 0; ks < 2; ++ks) {
            union { bf16x8 v; unsigned u[4]; } t;
            if (row < NNODES) {
                const float* ap = zin + (size_t)row * D + ks * 32 + lg * 8;
                float4 x0 = *(const float4*)ap;
                float4 x1 = *(const float4*)(ap + 4);
                t.u[0] = pk2(x0.x, x0.y); t.u[1] = pk2(x0.z, x0.w);
                t.u[2] = pk2(x1.x, x1.y); t.u[3] = pk2(x1.z, x1.w);
            } else {
                t.u[0] = t.u[1] = t.u[2] = t.u[3] = 0;
            }
            afrag[rt][ks] = t.v;
        }
    }
    f32x4 acc[8][2];
#pragma unroll
    for (int ct = 0; ct < 8; ++ct) {
        float b = b1[l * D2 + ct * 16 + lr];
#pragma unroll
        for (int rt = 0; rt < 2; ++rt) acc[ct][rt] = (f32x4){b, b, b, b};
    }
#pragma unroll
    for (int ct = 0; ct < 8; ++ct) {
        int col = ct * 16 + lr;
#pragma unroll
        for (int ks = 0; ks < 2; ++ks) {
            bf16x8 whi = *(const bf16x8*)&sWhi[col][ks * 32 + lg * 8];
            bf16x8 wlo = *(const bf16x8*)&sWlo[col][ks * 32 + lg * 8];
#pragma unroll
            for (int rt = 0; rt < 2; ++rt) {
                acc[ct][rt] = __builtin_amdgcn_mfma_f32_16x16x32_bf16(afrag[rt][ks], whi,
                                                                      acc[ct][rt], 0, 0, 0);
                acc[ct][rt] = __builtin_amdgcn_mfma_f32_16x16x32_bf16(afrag[rt][ks], wlo,
                                                                      acc[ct][rt], 0, 0, 0);
            }
        }
    }
#pragma unroll
    for (int ct = 0; ct < 8; ++ct) {
        int col = ct * 16 + lr;
        float s = 0.f, q = 0.f;
#pragma unroll
        for (int rt = 0; rt < 2; ++rt) {
            int rbase = rowA0 + rt * 16 + lg * 4;
#pragma unroll
            for (int j = 0; j < 4; ++j) {
                int row = rbase + j;
                if (row < NNODES) {
                    float v = acc[ct][rt][j];
                    tbf[(size_t)row * D2 + col] = __float2bfloat16(v);
                    s += v; q += v * v;
                }
            }
        }
        atomicAdd(&sSum[col], s);
        atomicAdd(&sSq[col], q);
    }
    __syncthreads();
    if (threadIdx.x < D2) {
        atomicAdd(&stats1[threadIdx.x], sSum[threadIdx.x]);
        atomicAdd(&stats1[D2 + threadIdx.x], sSq[threadIdx.x]);
    }
}

// ---------------- GEMM2 (MFMA): z2 = relu(bn(tbf)) @ W2 + b2 (+ BN stats of z2) ----------
__global__ __launch_bounds__(256) void k_gemm2(const __hip_bfloat16* __restrict__ tbf,
                                               const float* __restrict__ stats1,
                                               const float* __restrict__ W2,
                                               const float* __restrict__ b2, int l,
                                               float* __restrict__ z2,
                                               float* __restrict__ stats2) {
    __shared__ __hip_bfloat16 sWhi[D][136];
    __shared__ __hip_bfloat16 sWlo[D][136];
    __shared__ float sMu[D2], sRs[D2];
    __shared__ float sSum[D], sSq[D];
    const float* Wp = W2 + l * D2 * D;
    for (int i = threadIdx.x; i < D2 * D; i += 256) {
        int k = i >> 6, c = i & 63;
        float w = Wp[i];
        __hip_bfloat16 hi = __float2bfloat16(w);
        sWhi[c][k] = hi;
        sWlo[c][k] = __float2bfloat16(w - __bfloat162float(hi));
    }
    if (threadIdx.x < D2) {
        const float invN = 1.f / NNODES;
        float mu = stats1[threadIdx.x] * invN;
        float var = stats1[D2 + threadIdx.x] * invN - mu * mu;
        sMu[threadIdx.x] = mu;
        sRs[threadIdx.x] = rsqrtf(var + BN_EPS);
    }
    if (threadIdx.x < D) { sSum[threadIdx.x] = 0.f; sSq[threadIdx.x] = 0.f; }
    __syncthreads();
    int wid = threadIdx.x >> 6, lane = threadIdx.x & 63;
    int lr = lane & 15, lg = lane >> 4;
    int rowA0 = blockIdx.x * 128 + wid * 32;
    f32x4 acc[4][2];
#pragma unroll
    for (int ct = 0; ct < 4; ++ct) {
        float b = b2[l * D + ct * 16 + lr];
#pragma unroll
        for (int rt = 0; rt < 2; ++rt) acc[ct][rt] = (f32x4){b, b, b, b};
    }
#pragma unroll
    for (int ks = 0; ks < 4; ++ks) {
        int kb = ks * 32 + lg * 8;
        float4 mu0 = *(const float4*)&sMu[kb];
        float4 mu1 = *(const float4*)&sMu[kb + 4];
        float4 rs0 = *(const float4*)&sRs[kb];
        float4 rs1 = *(const float4*)&sRs[kb + 4];
        bf16x8 afrag[2];
#pragma unroll
        for (int rt = 0; rt < 2; ++rt) {
            int row = rowA0 + rt * 16 + lr;
            union { bf16x8 v; unsigned u[4]; } t;
            if (row < NNODES) {
                const __hip_bfloat16* tp = tbf + (size_t)row * D2 + kb;
                uint2 t0 = *(const uint2*)tp;
                uint2 t1 = *(const uint2*)(tp + 4);
                float v0 = fmaxf((blo(t0.x) - mu0.x) * rs0.x + BN_BIAS, 0.f);
                float v1 = fmaxf((bhi(t0.x) - mu0.y) * rs0.y + BN_BIAS, 0.f);
                float v2 = fmaxf((blo(t0.y) - mu0.z) * rs0.z + BN_BIAS, 0.f);
                float v3 = fmaxf((bhi(t0.y) - mu0.w) * rs0.w + BN_BIAS, 0.f);
                float v4 = fmaxf((blo(t1.x) - mu1.x) * rs1.x + BN_BIAS, 0.f);
                float v5 = fmaxf((bhi(t1.x) - mu1.y) * rs1.y + BN_BIAS, 0.f);
                float v6 = fmaxf((blo(t1.y) - mu1.z) * rs1.z + BN_BIAS, 0.f);
                float v7 = fmaxf((bhi(t1.y) - mu1.w) * rs1.w + BN_BIAS, 0.f);
                t.u[0] = pk2(v0, v1); t.u[1] = pk2(v2, v3);
                t.u[2] = pk2(v4, v5); t.u[3] = pk2(v6, v7);
            } else {
                t.u[0] = t.u[1] = t.u[2] = t.u[3] = 0;
            }
            afrag[rt] = t.v;
        }
#pragma unroll
        for (int ct = 0; ct < 4; ++ct) {
            int col = ct * 16 + lr;
            bf16x8 whi = *(const bf16x8*)&sWhi[col][kb];
            bf16x8 wlo = *(const bf16x8*)&sWlo[col][kb];
#pragma unroll
            for (int rt = 0; rt < 2; ++rt) {
                acc[ct][rt] = __builtin_amdgcn_mfma_f32_16x16x32_bf16(afrag[rt], whi,
                                                                      acc[ct][rt], 0, 0, 0);
                acc[ct][rt] = __builtin_amdgcn_mfma_f32_16x16x32_bf16(afrag[rt], wlo,
                                                                      acc[ct][rt], 0, 0, 0);
            }
        }
    }
#pragma unroll
    for (int ct = 0; ct < 4; ++ct) {
        int col = ct * 16 + lr;
        float s = 0.f, q = 0.f;
#pragma unroll
        for (int rt = 0; rt < 2; ++rt) {
            int rbase = rowA0 + rt * 16 + lg * 4;
#pragma unroll
            for (int j = 0; j < 4; ++j) {
                int row = rbase + j;
                if (row < NNODES) {
                    float v = acc[ct][rt][j];
                    z2[(size_t)row * D + col] = v;
                    s += v; q += v * v;
                }
            }
        }
        atomicAdd(&sSum[col], s);
        atomicAdd(&sSq[col], q);
    }
    __syncthreads();
    if (threadIdx.x < D) {
        atomicAdd(&stats2[threadIdx.x], sSum[threadIdx.x]);
        atomicAdd(&stats2[D + threadIdx.x], sSq[threadIdx.x]);
    }
}

// ------- fused: hin = relu(bn(z2)) + vn[batch]; hbf shadow; zin init for NEXT layer -------
__global__ __launch_bounds__(256) void k_bnprep(const float* __restrict__ z2,
                                                const float* __restrict__ stats2,
                                                const float* __restrict__ vn,
                                                const int* __restrict__ batch,
                                                const float* __restrict__ eps, int lnext,
                                                float* __restrict__ hin,
                                                __hip_bfloat16* __restrict__ hbf,
                                                float* __restrict__ zin) {
    int idx = blockIdx.x * 256 + threadIdx.x;
    if (idx >= NNODES * D) return;
    int c = idx & 63, row = idx >> 6;
    const float invN = 1.f / NNODES;
    float mu = stats2[c] * invN;
    float var = stats2[D + c] * invN - mu * mu;
    float rstd = rsqrtf(var + BN_EPS);
    float v = (z2[idx] - mu) * rstd + BN_BIAS;
    v = fmaxf(v, 0.f);
    v += vn[batch[row] * D + c];
    hin[idx] = v;
    hbf[idx] = __float2bfloat16(v);
    zin[idx] = (1.f + eps[lnext]) * v;
}

// ---------------- fused final: bn(z2) -> node att + per-node edge projections ----------------
__global__ __launch_bounds__(256) void k_finish_att_proj(const float* __restrict__ z2,
                                                         const float* __restrict__ stats2,
                                                         const float* __restrict__ Wna,
                                                         const float* __restrict__ bna,
                                                         const float* __restrict__ Wea,
                                                         float* __restrict__ proj,
                                                         float* __restrict__ out) {
    int wave = threadIdx.x >> 6, lane = threadIdx.x & 63;
    int row = blockIdx.x * 4 + wave;
    if (row >= NNODES) return;
    const float invN = 1.f / NNODES;
    float mu = stats2[lane] * invN;
    float var = stats2[D + lane] * invN - mu * mu;
    float rstd = rsqrtf(var + BN_EPS);
    float v = (z2[row * D + lane] - mu) * rstd + BN_BIAS;
    float n0 = v * Wna[lane * 2 + 0];
    float n1 = v * Wna[lane * 2 + 1];
    float pa0 = v * Wea[lane * 2 + 0];
    float pa1 = v * Wea[lane * 2 + 1];
    float pb0 = v * Wea[(D + lane) * 2 + 0];
    float pb1 = v * Wea[(D + lane) * 2 + 1];
#pragma unroll
    for (int o = 32; o; o >>= 1) {
        n0 += __shfl_xor(n0, o); n1 += __shfl_xor(n1, o);
        pa0 += __shfl_xor(pa0, o); pa1 += __shfl_xor(pa1, o);
        pb0 += __shfl_xor(pb0, o); pb1 += __shfl_xor(pb1, o);
    }
    if (lane == 0) {
        out[row] = 1.f / (1.f + expf((n0 + bna[0]) - (n1 + bna[1])));
        proj[row * 4 + 0] = pa0;
        proj[row * 4 + 1] = pa1;
        proj[row * 4 + 2] = pb0;
        proj[row * 4 + 3] = pb1;
    }
}

// ---------------- edge attention from projection tables ----------------
__global__ __launch_bounds__(256) void k_edge_final(const int* __restrict__ ei,
                                                    const float* __restrict__ proj,
                                                    const float* __restrict__ bea,
                                                    float* __restrict__ out) {
    int e = blockIdx.x * 256 + threadIdx.x;
    if (e >= NEDGES) return;
    int src = ei[e], dst = ei[NEDGES + e];
    float4 ps = *(const float4*)&proj[src * 4];
    float4 pd = *(const float4*)&proj[dst * 4];
    float s0 = ps.x + pd.z + bea[0];
    float s1 = ps.y + pd.w + bea[1];
    out[NNODES + e] = 1.f / (1.f + expf(s0 - s1));
}

// ---------------- vt += segment_sum(hin) over contiguous row chunks ----------------
__global__ __launch_bounds__(256) void k_vt(const float* __restrict__ hin,
                                            const int* __restrict__ batch,
                                            float* __restrict__ vt) {
    int wave = threadIdx.x >> 6, lane = threadIdx.x & 63;
    int wid = blockIdx.x * 4 + wave;
    int r0 = wid * 64;
    if (r0 >= NNODES) return;
    int r1 = min(r0 + 64, NNODES);
    int g = batch[r0];
    float acc = 0.f;
    for (int r = r0; r < r1; ++r) {
        int gb = batch[r];
        if (gb != g) {
            atomicAdd(&vt[g * D + lane], acc);
            acc = 0.f; g = gb;
        }
        acc += hin[r * D + lane];
    }
    atomicAdd(&vt[g * D + lane], acc);
}

// ---------------- vn-MLP stage 1: ucm[col][row] = relu(bn((vt+vn) @ Wv1 + bv1)) ----------------
__global__ __launch_bounds__(256) void k_vn1(const float* __restrict__ vt,
                                             const float* __restrict__ vn,
                                             const float* __restrict__ Wv1,
                                             const float* __restrict__ bv1, int l,
                                             float* __restrict__ ucm) {
    __shared__ float sV[NG * 65];
    __shared__ float sW[NG * 4];
    int c0 = blockIdx.x * 4;
    for (int i = threadIdx.x; i < NG * D; i += 256) {
        int r = i >> 6, c = i & 63;
        sV[r * 65 + c] = vt[i] + vn[i];
    }
    {
        int k = threadIdx.x >> 2, c = threadIdx.x & 3;
        sW[threadIdx.x] = Wv1[l * D * D2 + k * D2 + c0 + c];
    }
    __syncthreads();
    int lane = threadIdx.x & 63, w = threadIdx.x >> 6;
    float acc = bv1[l * D2 + c0 + w];
#pragma unroll
    for (int k = 0; k < D; ++k) acc += sV[lane * 65 + k] * sW[k * 4 + w];
    float s = acc, sq = acc * acc;
#pragma unroll
    for (int o = 32; o; o >>= 1) { s += __shfl_xor(s, o); sq += __shfl_xor(sq, o); }
    float mu = s * (1.f / NG);
    float rstd = rsqrtf(sq * (1.f / NG) - mu * mu + BN_EPS);
    ucm[(c0 + w) * NG + lane] = fmaxf((acc - mu) * rstd + BN_BIAS, 0.f);
}

// ---------------- vn-MLP stage 2: vn = relu(bn(ucm^T @ Wv2 + bv2)) ----------------
__global__ __launch_bounds__(256) void k_vn2(const float* __restrict__ ucm,
                                             const float* __restrict__ Wv2,
                                             const float* __restrict__ bv2, int l,
                                             float* __restrict__ vn) {
    __shared__ float sU[D2 * NG];
    __shared__ float sW[D2 * 4];
    int c0 = blockIdx.x * 4;
    for (int i = threadIdx.x; i < D2 * NG; i += 256) sU[i] = ucm[i];
    for (int i = threadIdx.x; i < D2 * 4; i += 256) {
        int k = i >> 2, c = i & 3;
        sW[i] = Wv2[l * D2 * D + k * D + c0 + c];
    }
    __syncthreads();
    int lane = threadIdx.x & 63, w = threadIdx.x >> 6;
    float acc = bv2[l * D + c0 + w];
#pragma unroll
    for (int k = 0; k < D2; ++k) acc += sU[k * NG + lane] * sW[k * 4 + w];
    float s = acc, sq = acc * acc;
#pragma unroll
    for (int o = 32; o; o >>= 1) { s += __shfl_xor(s, o); sq += __shfl_xor(sq, o); }
    float mu = s * (1.f / NG);
    float rstd = rsqrtf(sq * (1.f / NG) - mu * mu + BN_EPS);
    vn[lane * D + c0 + w] = fmaxf((acc - mu) * rstd + BN_BIAS, 0.f);
}

extern "C" void kernel_launch(void* const* d_in, const int* in_sizes, int n_in,
                              void* d_out, int out_size, void* d_ws, size_t ws_size,
                              hipStream_t stream) {
    const float* x    = (const float*)d_in[0];
    const float* ea   = (const float*)d_in[1];
    const int*   ei   = (const int*)d_in[2];
    const int*   batch= (const int*)d_in[3];
    const float* Wenc = (const float*)d_in[4];
    const float* benc = (const float*)d_in[5];
    const float* We   = (const float*)d_in[6];
    const float* be   = (const float*)d_in[7];
    const float* eps  = (const float*)d_in[8];
    const float* W1   = (const float*)d_in[9];
    const float* b1   = (const float*)d_in[10];
    const float* W2   = (const float*)d_in[11];
    const float* b2   = (const float*)d_in[12];
    const float* Wv1  = (const float*)d_in[13];
    const float* bv1  = (const float*)d_in[14];
    const float* Wv2  = (const float*)d_in[15];
    const float* bv2  = (const float*)d_in[16];
    const float* Wea  = (const float*)d_in[17];
    const float* bea  = (const float*)d_in[18];
    const float* Wna  = (const float*)d_in[19];
    const float* bna  = (const float*)d_in[20];
    float* out = (float*)d_out;

    float* ws   = (float*)d_ws;
    float* hin  = ws;                              // [N*D]
    float* zin  = hin + (size_t)NNODES * D;        // [N*D]  (z2 overlays zin)
    float* t    = zin + (size_t)NNODES * D;        // slot [N*D2] f32; used as bf16 [N*D2]
    float* proj = t   + (size_t)NNODES * D2;       // [N*4]
    uint4* e32  = (uint4*)(proj + (size_t)NNODES * 4);      // [E * 32B], 16B-aligned
    __hip_bfloat16* hbf = (__hip_bfloat16*)(e32 + (size_t)NEDGES * 2);   // [N*D]
    // ---- contiguous zero-region: vn | vt0 | vt1 | stats(1536) | deg ----
    float* vn    = (float*)(hbf + (size_t)NNODES * D);
    float* vt0   = vn  + NG * D;
    float* vt1   = vt0 + NG * D;
    float* stats = vt1 + NG * D;                   // statsA: l*256 (0..767); statsB: 768+l*128
    int*   deg   = (int*)(stats + 1536);
    // ---- end zero-region ----
    int*   cursor = deg + NNODES;
    int*   bsum   = cursor + NNODES;
    int*   bbase  = bsum + NSB;
    float* ucm    = (float*)(bbase + NSB);         // [D2*NG]

    __hip_bfloat16* tbf = (__hip_bfloat16*)t;
    float* z2 = zin;   // overlay: zin dead after gemm1

    size_t zero_bytes = (size_t)(3 * NG * D + 1536) * 4 + (size_t)NNODES * 4;
    hipMemsetAsync(vn, 0, zero_bytes, stream);
    k_enc<<<NNODES / 4, 256, 0, stream>>>(x, Wenc, benc, eps, hin, hbf, zin);
    k_hist<<<(NEDGES + 255) / 256, 256, 0, stream>>>(ei, deg);
    k_scansum<<<NSB, 256, 0, stream>>>(deg, bsum);
    k_scanbase<<<1, 256, 0, stream>>>(bsum, bbase);
    k_scanwrite<<<NSB, 256, 0, stream>>>(deg, bbase, cursor);
    k_scatter<<<(NEDGES + 255) / 256, 256, 0, stream>>>(ei, ea, cursor, (unsigned*)e32);

    for (int l = 0; l < 3; ++l) {
        float* statsA = stats + l * 256;
        float* statsB = stats + 768 + l * 128;
        if (l < 2) {
            float* vtb = (l == 0) ? vt0 : vt1;
            k_vt<<<(NNODES / 64 + 4) / 4, 256, 0, stream>>>(hin, batch, vtb);
            k_agg<<<NEDGES / (EPW * 4), 256, 0, stream>>>(e32, We, be, l, hbf, zin);
            k_vn1<<<32, 256, 0, stream>>>(vtb, vn, Wv1, bv1, l, ucm);
            k_vn2<<<16, 256, 0, stream>>>(ucm, Wv2, bv2, l, vn);
        } else {
            k_agg<<<NEDGES / (EPW * 4), 256, 0, stream>>>(e32, We, be, l, hbf, zin);
        }
        k_gemm1<<<(NNODES + 127) / 128, 256, 0, stream>>>(zin, W1, b1, l, tbf, statsA);
        k_gemm2<<<(NNODES + 127) / 128, 256, 0, stream>>>(tbf, statsA, W2, b2, l, z2, statsB);
        if (l < 2) {
            k_bnprep<<<NNODES * D / 256, 256, 0, stream>>>(z2, statsB, vn, batch, eps,
                                                           l + 1, hin, hbf, zin);
        } else {
            k_finish_att_proj<<<NNODES / 4, 256, 0, stream>>>(z2, statsB, Wna, bna, Wea,
                                                              proj, out);
        }
    }
    k_edge_final<<<(NEDGES + 255) / 256, 256, 0, stream>>>(ei, proj, bea, out);
}

// Round 18
// 479.965 us; speedup vs baseline: 1.0435x; 1.0435x over previous
//
#include <hip/hip_runtime.h>
#include <hip/hip_bf16.h>

#define NNODES 50000
#define NEDGES 800000
#define NG 64
#define D 64
#define D2 128
#define INDIM 39
#define EDIM 10
#define EPW 16             // edges per wave in k_agg (exact: 12500*4*16 = 800000)
#define BN_EPS 1e-5f
#define BN_BIAS 1e-4f
#define NSB ((NNODES + 255) / 256)   // 196 scan blocks

typedef __attribute__((ext_vector_type(8))) short bf16x8;
typedef __attribute__((ext_vector_type(4))) float f32x4;

__device__ __forceinline__ float blo(unsigned u) {
    union { unsigned i; float f; } c; c.i = u << 16; return c.f;
}
__device__ __forceinline__ float bhi(unsigned u) {
    union { unsigned i; float f; } c; c.i = u & 0xffff0000u; return c.f;
}
__device__ __forceinline__ unsigned pk2(float a, float b) {
    __hip_bfloat16 ba = __float2bfloat16(a), bb = __float2bfloat16(b);
    return ((unsigned)*(unsigned short*)&bb << 16) | (unsigned)*(unsigned short*)&ba;
}

// ---------------- encoder: hin = x @ Wenc + benc (+ bf16 shadow, + zin init) ----------------
__global__ __launch_bounds__(256) void k_enc(const float* __restrict__ x,
                                             const float* __restrict__ Wenc,
                                             const float* __restrict__ benc,
                                             const float* __restrict__ eps,
                                             float* __restrict__ hin,
                                             __hip_bfloat16* __restrict__ hbf,
                                             float* __restrict__ zin) {
    __shared__ float sW[INDIM * D];
    for (int i = threadIdx.x; i < INDIM * D; i += 256) sW[i] = Wenc[i];
    __syncthreads();
    int wave = threadIdx.x >> 6, lane = threadIdx.x & 63;
    int row = blockIdx.x * 4 + wave;
    if (row >= NNODES) return;
    float xv = (lane < INDIM) ? x[row * INDIM + lane] : 0.f;
    float acc = benc[lane];
#pragma unroll
    for (int k = 0; k < INDIM; ++k) acc += __shfl(xv, k) * sW[k * D + lane];
    hin[row * D + lane] = acc;
    hbf[row * D + lane] = __float2bfloat16(acc);
    zin[row * D + lane] = (1.f + eps[0]) * acc;
}

// ---------------- CSR build ----------------
__global__ __launch_bounds__(256) void k_hist(const int* __restrict__ ei,
                                              int* __restrict__ deg) {
    int e = blockIdx.x * 256 + threadIdx.x;
    if (e < NEDGES) atomicAdd(&deg[ei[NEDGES + e]], 1);
}

__global__ __launch_bounds__(256) void k_scansum(const int* __restrict__ deg,
                                                 int* __restrict__ bsum) {
    int i = blockIdx.x * 256 + threadIdx.x;
    int v = (i < NNODES) ? deg[i] : 0;
#pragma unroll
    for (int o = 32; o; o >>= 1) v += __shfl_xor(v, o);
    __shared__ int ws[4];
    if ((threadIdx.x & 63) == 0) ws[threadIdx.x >> 6] = v;
    __syncthreads();
    if (threadIdx.x == 0) bsum[blockIdx.x] = ws[0] + ws[1] + ws[2] + ws[3];
}

__global__ __launch_bounds__(256) void k_scanbase(const int* __restrict__ bsum,
                                                  int* __restrict__ bbase) {
    __shared__ int s[256];
    int t = threadIdx.x;
    int v = (t < NSB) ? bsum[t] : 0;
    s[t] = v;
    __syncthreads();
    for (int o = 1; o < 256; o <<= 1) {
        int u = (t >= o) ? s[t - o] : 0;
        __syncthreads();
        s[t] += u;
        __syncthreads();
    }
    if (t < NSB) bbase[t] = s[t] - v;
}

__global__ __launch_bounds__(256) void k_scanwrite(const int* __restrict__ deg,
                                                   const int* __restrict__ bbase,
                                                   int* __restrict__ cursor) {
    __shared__ int s[256];
    int t = threadIdx.x;
    int i = blockIdx.x * 256 + t;
    int v = (i < NNODES) ? deg[i] : 0;
    s[t] = v;
    __syncthreads();
    for (int o = 1; o < 256; o <<= 1) {
        int u = (t >= o) ? s[t - o] : 0;
        __syncthreads();
        s[t] += u;
        __syncthreads();
    }
    int excl = bbase[blockIdx.x] + s[t] - v;
    if (i < NNODES) cursor[i] = excl;
}

// scatter fused 32B edge record {src, dst, 5 x bf16-pair} into CSR (dst-sorted) order
__global__ __launch_bounds__(256) void k_scatter(const int* __restrict__ ei,
                                                 const float* __restrict__ ea,
                                                 int* __restrict__ cursor,
                                                 uint4* __restrict__ e32) {
    int e = blockIdx.x * 256 + threadIdx.x;
    if (e >= NEDGES) return;
    int s = ei[e], d = ei[NEDGES + e];
    int p = atomicAdd(&cursor[d], 1);
    unsigned u[5];
#pragma unroll
    for (int i = 0; i < 5; ++i)
        u[i] = pk2(ea[(size_t)e * EDIM + 2 * i], ea[(size_t)e * EDIM + 2 * i + 1]);
    uint4 lo, hi;
    lo.x = (unsigned)s; lo.y = (unsigned)d; lo.z = u[0]; lo.w = u[1];
    hi.x = u[2]; hi.y = u[3]; hi.z = u[4]; hi.w = 0;
    e32[(size_t)p * 2] = lo;
    e32[(size_t)p * 2 + 1] = hi;
}

// ---------------- aggregate, edge-balanced, scalar edge stream ----------------
__global__ __launch_bounds__(256) void k_agg(const uint4* __restrict__ e32,
                                             const float* __restrict__ We,
                                             const float* __restrict__ be, int l,
                                             const __hip_bfloat16* __restrict__ hbf,
                                             float* __restrict__ zin) {
    int wid = __builtin_amdgcn_readfirstlane(threadIdx.x >> 6);
    int lane = threadIdx.x & 63;
    int j0 = (blockIdx.x * 4 + wid) * EPW;
    const float* Wl = We + l * EDIM * D;
    float w[EDIM];
#pragma unroll
    for (int k = 0; k < EDIM; ++k) w[k] = Wl[k * D + lane];
    float bias = be[l * D + lane];
    float acc = 0.f;
    const uint4* ep = e32 + (size_t)j0 * 2;
    int cur = (int)ep[0].y;
#define EMB(lo, hi, m)                                                                   \
    {                                                                                    \
        m = bias;                                                                        \
        m += blo(lo.z) * w[0] + bhi(lo.z) * w[1] + blo(lo.w) * w[2] + bhi(lo.w) * w[3];  \
        m += blo(hi.x) * w[4] + bhi(hi.x) * w[5] + blo(hi.y) * w[6] + bhi(hi.y) * w[7];  \
        m += blo(hi.z) * w[8] + bhi(hi.z) * w[9];                                        \
    }
#define STEP(dd, mm, hh)                                                                 \
    {                                                                                    \
        if (dd != cur) {                                                                 \
            atomicAdd(&zin[(size_t)cur * D + lane], acc);                                \
            acc = 0.f; cur = dd;                                                         \
        }                                                                                \
        acc += fmaxf(mm + hh, 0.f);                                                      \
    }
#pragma unroll 2
    for (int it = 0; it < EPW; it += 4) {
        const uint4* r = ep + it * 2;
        uint4 lo0 = r[0], hi0 = r[1];
        uint4 lo1 = r[2], hi1 = r[3];
        uint4 lo2 = r[4], hi2 = r[5];
        uint4 lo3 = r[6], hi3 = r[7];
        float hv0 = __bfloat162float(hbf[(size_t)lo0.x * D + lane]);
        float hv1 = __bfloat162float(hbf[(size_t)lo1.x * D + lane]);
        float hv2 = __bfloat162float(hbf[(size_t)lo2.x * D + lane]);
        float hv3 = __bfloat162float(hbf[(size_t)lo3.x * D + lane]);
        float m0, m1, m2, m3;
        EMB(lo0, hi0, m0) EMB(lo1, hi1, m1) EMB(lo2, hi2, m2) EMB(lo3, hi3, m3)
        STEP((int)lo0.y, m0, hv0)
        STEP((int)lo1.y, m1, hv1)
        STEP((int)lo2.y, m2, hv2)
        STEP((int)lo3.y, m3, hv3)
    }
#undef EMB
#undef STEP
    atomicAdd(&zin[(size_t)cur * D + lane], acc);
}

// ---------------- GEMM1 (MFMA): tbf = bf16(zin @ W1 + b1) (+ fp32 BN stats) ----------------
__global__ __launch_bounds__(256) void k_gemm1(const float* __restrict__ zin,
                                               const float* __restrict__ W1,
                                               const float* __restrict__ b1, int l,
                                               __hip_bfloat16* __restrict__ tbf,
                                               float* __restrict__ stats1) {
    __shared__ __hip_bfloat16 sWhi[D2][72];
    __shared__ __hip_bfloat16 sWlo[D2][72];
    __shared__ float sSum[D2], sSq[D2];
    const float* Wp = W1 + l * D * D2;
    for (int i = threadIdx.x; i < D * D2; i += 256) {
        int k = i >> 7, c = i & 127;
        float w = Wp[i];
        __hip_bfloat16 hi = __float2bfloat16(w);
        sWhi[c][k] = hi;
        sWlo[c][k] = __float2bfloat16(w - __bfloat162float(hi));
    }
    if (threadIdx.x < D2) { sSum[threadIdx.x] = 0.f; sSq[threadIdx.x] = 0.f; }
    __syncthreads();
    int wid = threadIdx.x >> 6, lane = threadIdx.x & 63;
    int lr = lane & 15, lg = lane >> 4;
    int rowA0 = blockIdx.x * 128 + wid * 32;
    bf16x8 afrag[2][2];
#pragma unroll
    for (int rt = 0; rt < 2; ++rt) {
        int row = rowA0 + rt * 16 + lr;
#pragma unroll
        for (int ks = 0; ks < 2; ++ks) {
            union { bf16x8 v; unsigned u[4]; } t;
            if (row < NNODES) {
                const float* ap = zin + (size_t)row * D + ks * 32 + lg * 8;
                float4 x0 = *(const float4*)ap;
                float4 x1 = *(const float4*)(ap + 4);
                t.u[0] = pk2(x0.x, x0.y); t.u[1] = pk2(x0.z, x0.w);
                t.u[2] = pk2(x1.x, x1.y); t.u[3] = pk2(x1.z, x1.w);
            } else {
                t.u[0] = t.u[1] = t.u[2] = t.u[3] = 0;
            }
            afrag[rt][ks] = t.v;
        }
    }
    f32x4 acc[8][2];
#pragma unroll
    for (int ct = 0; ct < 8; ++ct) {
        float b = b1[l * D2 + ct * 16 + lr];
#pragma unroll
        for (int rt = 0; rt < 2; ++rt) acc[ct][rt] = (f32x4){b, b, b, b};
    }
#pragma unroll
    for (int ct = 0; ct < 8; ++ct) {
        int col = ct * 16 + lr;
#pragma unroll
        for (int ks = 0; ks < 2; ++ks) {
            bf16x8 whi = *(const bf16x8*)&sWhi[col][ks * 32 + lg * 8];
            bf16x8 wlo = *(const bf16x8*)&sWlo[col][ks * 32 + lg * 8];
#pragma unroll
            for (int rt = 0; rt < 2; ++rt) {
                acc[ct][rt] = __builtin_amdgcn_mfma_f32_16x16x32_bf16(afrag[rt][ks], whi,
                                                                      acc[ct][rt], 0, 0, 0);
                acc[ct][rt] = __builtin_amdgcn_mfma_f32_16x16x32_bf16(afrag[rt][ks], wlo,
                                                                      acc[ct][rt], 0, 0, 0);
            }
        }
    }
#pragma unroll
    for (int ct = 0; ct < 8; ++ct) {
        int col = ct * 16 + lr;
        float s = 0.f, q = 0.f;
#pragma unroll
        for (int rt = 0; rt < 2; ++rt) {
            int rbase = rowA0 + rt * 16 + lg * 4;
#pragma unroll
            for (int j = 0; j < 4; ++j) {
                int row = rbase + j;
                if (row < NNODES) {
                    float v = acc[ct][rt][j];
                    tbf[(size_t)row * D2 + col] = __float2bfloat16(v);
                    s += v; q += v * v;
                }
            }
        }
        atomicAdd(&sSum[col], s);
        atomicAdd(&sSq[col], q);
    }
    __syncthreads();
    if (threadIdx.x < D2) {
        atomicAdd(&stats1[threadIdx.x], sSum[threadIdx.x]);
        atomicAdd(&stats1[D2 + threadIdx.x], sSq[threadIdx.x]);
    }
}

// ---------------- GEMM2 (MFMA): z2 = relu(bn(tbf)) @ W2 + b2 (+ BN stats of z2) ----------
__global__ __launch_bounds__(256) void k_gemm2(const __hip_bfloat16* __restrict__ tbf,
                                               const float* __restrict__ stats1,
                                               const float* __restrict__ W2,
                                               const float* __restrict__ b2, int l,
                                               float* __restrict__ z2,
                                               float* __restrict__ stats2) {
    __shared__ __hip_bfloat16 sWhi[D][136];
    __shared__ __hip_bfloat16 sWlo[D][136];
    __shared__ float sMu[D2], sRs[D2];
    __shared__ float sSum[D], sSq[D];
    const float* Wp = W2 + l * D2 * D;
    for (int i = threadIdx.x; i < D2 * D; i += 256) {
        int k = i >> 6, c = i & 63;
        float w = Wp[i];
        __hip_bfloat16 hi = __float2bfloat16(w);
        sWhi[c][k] = hi;
        sWlo[c][k] = __float2bfloat16(w - __bfloat162float(hi));
    }
    if (threadIdx.x < D2) {
        const float invN = 1.f / NNODES;
        float mu = stats1[threadIdx.x] * invN;
        float var = stats1[D2 + threadIdx.x] * invN - mu * mu;
        sMu[threadIdx.x] = mu;
        sRs[threadIdx.x] = rsqrtf(var + BN_EPS);
    }
    if (threadIdx.x < D) { sSum[threadIdx.x] = 0.f; sSq[threadIdx.x] = 0.f; }
    __syncthreads();
    int wid = threadIdx.x >> 6, lane = threadIdx.x & 63;
    int lr = lane & 15, lg = lane >> 4;
    int rowA0 = blockIdx.x * 128 + wid * 32;
    f32x4 acc[4][2];
#pragma unroll
    for (int ct = 0; ct < 4; ++ct) {
        float b = b2[l * D + ct * 16 + lr];
#pragma unroll
        for (int rt = 0; rt < 2; ++rt) acc[ct][rt] = (f32x4){b, b, b, b};
    }
#pragma unroll
    for (int ks = 0; ks < 4; ++ks) {
        int kb = ks * 32 + lg * 8;
        float4 mu0 = *(const float4*)&sMu[kb];
        float4 mu1 = *(const float4*)&sMu[kb + 4];
        float4 rs0 = *(const float4*)&sRs[kb];
        float4 rs1 = *(const float4*)&sRs[kb + 4];
        bf16x8 afrag[2];
#pragma unroll
        for (int rt = 0; rt < 2; ++rt) {
            int row = rowA0 + rt * 16 + lr;
            union { bf16x8 v; unsigned u[4]; } t;
            if (row < NNODES) {
                const __hip_bfloat16* tp = tbf + (size_t)row * D2 + kb;
                uint2 t0 = *(const uint2*)tp;
                uint2 t1 = *(const uint2*)(tp + 4);
                float v0 = fmaxf((blo(t0.x) - mu0.x) * rs0.x + BN_BIAS, 0.f);
                float v1 = fmaxf((bhi(t0.x) - mu0.y) * rs0.y + BN_BIAS, 0.f);
                float v2 = fmaxf((blo(t0.y) - mu0.z) * rs0.z + BN_BIAS, 0.f);
                float v3 = fmaxf((bhi(t0.y) - mu0.w) * rs0.w + BN_BIAS, 0.f);
                float v4 = fmaxf((blo(t1.x) - mu1.x) * rs1.x + BN_BIAS, 0.f);
                float v5 = fmaxf((bhi(t1.x) - mu1.y) * rs1.y + BN_BIAS, 0.f);
                float v6 = fmaxf((blo(t1.y) - mu1.z) * rs1.z + BN_BIAS, 0.f);
                float v7 = fmaxf((bhi(t1.y) - mu1.w) * rs1.w + BN_BIAS, 0.f);
                t.u[0] = pk2(v0, v1); t.u[1] = pk2(v2, v3);
                t.u[2] = pk2(v4, v5); t.u[3] = pk2(v6, v7);
            } else {
                t.u[0] = t.u[1] = t.u[2] = t.u[3] = 0;
            }
            afrag[rt] = t.v;
        }
#pragma unroll
        for (int ct = 0; ct < 4; ++ct) {
            int col = ct * 16 + lr;
            bf16x8 whi = *(const bf16x8*)&sWhi[col][kb];
            bf16x8 wlo = *(const bf16x8*)&sWlo[col][kb];
#pragma unroll
            for (int rt = 0; rt < 2; ++rt) {
                acc[ct][rt] = __builtin_amdgcn_mfma_f32_16x16x32_bf16(afrag[rt], whi,
                                                                      acc[ct][rt], 0, 0, 0);
                acc[ct][rt] = __builtin_amdgcn_mfma_f32_16x16x32_bf16(afrag[rt], wlo,
                                                                      acc[ct][rt], 0, 0, 0);
            }
        }
    }
#pragma unroll
    for (int ct = 0; ct < 4; ++ct) {
        int col = ct * 16 + lr;
        float s = 0.f, q = 0.f;
#pragma unroll
        for (int rt = 0; rt < 2; ++rt) {
            int rbase = rowA0 + rt * 16 + lg * 4;
#pragma unroll
            for (int j = 0; j < 4; ++j) {
                int row = rbase + j;
                if (row < NNODES) {
                    float v = acc[ct][rt][j];
                    z2[(size_t)row * D + col] = v;
                    s += v; q += v * v;
                }
            }
        }
        atomicAdd(&sSum[col], s);
        atomicAdd(&sSq[col], q);
    }
    __syncthreads();
    if (threadIdx.x < D) {
        atomicAdd(&stats2[threadIdx.x], sSum[threadIdx.x]);
        atomicAdd(&stats2[D + threadIdx.x], sSq[threadIdx.x]);
    }
}

// ------- fused: hin = relu(bn(z2)) + vn[batch]; hbf shadow; zin init for NEXT layer -------
__global__ __launch_bounds__(256) void k_bnprep(const float* __restrict__ z2,
                                                const float* __restrict__ stats2,
                                                const float* __restrict__ vn,
                                                const int* __restrict__ batch,
                                                const float* __restrict__ eps, int lnext,
                                                float* __restrict__ hin,
                                                __hip_bfloat16* __restrict__ hbf,
                                                float* __restrict__ zin) {
    int idx = blockIdx.x * 256 + threadIdx.x;
    if (idx >= NNODES * D) return;
    int c = idx & 63, row = idx >> 6;
    const float invN = 1.f / NNODES;
    float mu = stats2[c] * invN;
    float var = stats2[D + c] * invN - mu * mu;
    float rstd = rsqrtf(var + BN_EPS);
    float v = (z2[idx] - mu) * rstd + BN_BIAS;
    v = fmaxf(v, 0.f);
    v += vn[batch[row] * D + c];
    hin[idx] = v;
    hbf[idx] = __float2bfloat16(v);
    zin[idx] = (1.f + eps[lnext]) * v;
}

// ---------------- fused final: bn(z2) -> node att + per-node edge projections ----------------
__global__ __launch_bounds__(256) void k_finish_att_proj(const float* __restrict__ z2,
                                                         const float* __restrict__ stats2,
                                                         const float* __restrict__ Wna,
                                                         const float* __restrict__ bna,
                                                         const float* __restrict__ Wea,
                                                         float* __restrict__ proj,
                                                         float* __restrict__ out) {
    int wave = threadIdx.x >> 6, lane = threadIdx.x & 63;
    int row = blockIdx.x * 4 + wave;
    if (row >= NNODES) return;
    const float invN = 1.f / NNODES;
    float mu = stats2[lane] * invN;
    float var = stats2[D + lane] * invN - mu * mu;
    float rstd = rsqrtf(var + BN_EPS);
    float v = (z2[row * D + lane] - mu) * rstd + BN_BIAS;
    float n0 = v * Wna[lane * 2 + 0];
    float n1 = v * Wna[lane * 2 + 1];
    float pa0 = v * Wea[lane * 2 + 0];
    float pa1 = v * Wea[lane * 2 + 1];
    float pb0 = v * Wea[(D + lane) * 2 + 0];
    float pb1 = v * Wea[(D + lane) * 2 + 1];
#pragma unroll
    for (int o = 32; o; o >>= 1) {
        n0 += __shfl_xor(n0, o); n1 += __shfl_xor(n1, o);
        pa0 += __shfl_xor(pa0, o); pa1 += __shfl_xor(pa1, o);
        pb0 += __shfl_xor(pb0, o); pb1 += __shfl_xor(pb1, o);
    }
    if (lane == 0) {
        out[row] = 1.f / (1.f + expf((n0 + bna[0]) - (n1 + bna[1])));
        proj[row * 4 + 0] = pa0;
        proj[row * 4 + 1] = pa1;
        proj[row * 4 + 2] = pb0;
        proj[row * 4 + 3] = pb1;
    }
}

// ---------------- edge attention from projection tables ----------------
__global__ __launch_bounds__(256) void k_edge_final(const int* __restrict__ ei,
                                                    const float* __restrict__ proj,
                                                    const float* __restrict__ bea,
                                                    float* __restrict__ out) {
    int e = blockIdx.x * 256 + threadIdx.x;
    if (e >= NEDGES) return;
    int src = ei[e], dst = ei[NEDGES + e];
    float4 ps = *(const float4*)&proj[src * 4];
    float4 pd = *(const float4*)&proj[dst * 4];
    float s0 = ps.x + pd.z + bea[0];
    float s1 = ps.y + pd.w + bea[1];
    out[NNODES + e] = 1.f / (1.f + expf(s0 - s1));
}

// ---------------- vt += segment_sum(hin) over contiguous row chunks ----------------
__global__ __launch_bounds__(256) void k_vt(const float* __restrict__ hin,
                                            const int* __restrict__ batch,
                                            float* __restrict__ vt) {
    int wave = threadIdx.x >> 6, lane = threadIdx.x & 63;
    int wid = blockIdx.x * 4 + wave;
    int r0 = wid * 64;
    if (r0 >= NNODES) return;
    int r1 = min(r0 + 64, NNODES);
    int g = batch[r0];
    float acc = 0.f;
    for (int r = r0; r < r1; ++r) {
        int gb = batch[r];
        if (gb != g) {
            atomicAdd(&vt[g * D + lane], acc);
            acc = 0.f; g = gb;
        }
        acc += hin[r * D + lane];
    }
    atomicAdd(&vt[g * D + lane], acc);
}

// ---------------- vn-MLP stage 1: ucm[col][row] = relu(bn((vt+vn) @ Wv1 + bv1)) ----------------
__global__ __launch_bounds__(256) void k_vn1(const float* __restrict__ vt,
                                             const float* __restrict__ vn,
                                             const float* __restrict__ Wv1,
                                             const float* __restrict__ bv1, int l,
                                             float* __restrict__ ucm) {
    __shared__ float sV[NG * 65];
    __shared__ float sW[NG * 4];
    int c0 = blockIdx.x * 4;
    for (int i = threadIdx.x; i < NG * D; i += 256) {
        int r = i >> 6, c = i & 63;
        sV[r * 65 + c] = vt[i] + vn[i];
    }
    {
        int k = threadIdx.x >> 2, c = threadIdx.x & 3;
        sW[threadIdx.x] = Wv1[l * D * D2 + k * D2 + c0 + c];
    }
    __syncthreads();
    int lane = threadIdx.x & 63, w = threadIdx.x >> 6;
    float acc = bv1[l * D2 + c0 + w];
#pragma unroll
    for (int k = 0; k < D; ++k) acc += sV[lane * 65 + k] * sW[k * 4 + w];
    float s = acc, sq = acc * acc;
#pragma unroll
    for (int o = 32; o; o >>= 1) { s += __shfl_xor(s, o); sq += __shfl_xor(sq, o); }
    float mu = s * (1.f / NG);
    float rstd = rsqrtf(sq * (1.f / NG) - mu * mu + BN_EPS);
    ucm[(c0 + w) * NG + lane] = fmaxf((acc - mu) * rstd + BN_BIAS, 0.f);
}

// ---------------- vn-MLP stage 2: vn = relu(bn(ucm^T @ Wv2 + bv2)) ----------------
__global__ __launch_bounds__(256) void k_vn2(const float* __restrict__ ucm,
                                             const float* __restrict__ Wv2,
                                             const float* __restrict__ bv2, int l,
                                             float* __restrict__ vn) {
    __shared__ float sU[D2 * NG];
    __shared__ float sW[D2 * 4];
    int c0 = blockIdx.x * 4;
    for (int i = threadIdx.x; i < D2 * NG; i += 256) sU[i] = ucm[i];
    for (int i = threadIdx.x; i < D2 * 4; i += 256) {
        int k = i >> 2, c = i & 3;
        sW[i] = Wv2[l * D2 * D + k * D + c0 + c];
    }
    __syncthreads();
    int lane = threadIdx.x & 63, w = threadIdx.x >> 6;
    float acc = bv2[l * D + c0 + w];
#pragma unroll
    for (int k = 0; k < D2; ++k) acc += sU[k * NG + lane] * sW[k * 4 + w];
    float s = acc, sq = acc * acc;
#pragma unroll
    for (int o = 32; o; o >>= 1) { s += __shfl_xor(s, o); sq += __shfl_xor(sq, o); }
    float mu = s * (1.f / NG);
    float rstd = rsqrtf(sq * (1.f / NG) - mu * mu + BN_EPS);
    vn[lane * D + c0 + w] = fmaxf((acc - mu) * rstd + BN_BIAS, 0.f);
}

extern "C" void kernel_launch(void* const* d_in, const int* in_sizes, int n_in,
                              void* d_out, int out_size, void* d_ws, size_t ws_size,
                              hipStream_t stream) {
    const float* x    = (const float*)d_in[0];
    const float* ea   = (const float*)d_in[1];
    const int*   ei   = (const int*)d_in[2];
    const int*   batch= (const int*)d_in[3];
    const float* Wenc = (const float*)d_in[4];
    const float* benc = (const float*)d_in[5];
    const float* We   = (const float*)d_in[6];
    const float* be   = (const float*)d_in[7];
    const float* eps  = (const float*)d_in[8];
    const float* W1   = (const float*)d_in[9];
    const float* b1   = (const float*)d_in[10];
    const float* W2   = (const float*)d_in[11];
    const float* b2   = (const float*)d_in[12];
    const float* Wv1  = (const float*)d_in[13];
    const float* bv1  = (const float*)d_in[14];
    const float* Wv2  = (const float*)d_in[15];
    const float* bv2  = (const float*)d_in[16];
    const float* Wea  = (const float*)d_in[17];
    const float* bea  = (const float*)d_in[18];
    const float* Wna  = (const float*)d_in[19];
    const float* bna  = (const float*)d_in[20];
    float* out = (float*)d_out;

    float* ws   = (float*)d_ws;
    float* hin  = ws;                              // [N*D]
    float* zin  = hin + (size_t)NNODES * D;        // [N*D]  (z2 overlays zin)
    float* t    = zin + (size_t)NNODES * D;        // slot [N*D2] f32; used as bf16 [N*D2]
    float* proj = t   + (size_t)NNODES * D2;       // [N*4]
    uint4* e32  = (uint4*)(proj + (size_t)NNODES * 4);      // [E * 32B], 16B-aligned
    __hip_bfloat16* hbf = (__hip_bfloat16*)(e32 + (size_t)NEDGES * 2);   // [N*D]
    // ---- contiguous zero-region: vn | vt0 | vt1 | stats(1536) | deg ----
    float* vn    = (float*)(hbf + (size_t)NNODES * D);
    float* vt0   = vn  + NG * D;
    float* vt1   = vt0 + NG * D;
    float* stats = vt1 + NG * D;                   // statsA: l*256 (0..767); statsB: 768+l*128
    int*   deg   = (int*)(stats + 1536);
    // ---- end zero-region ----
    int*   cursor = deg + NNODES;
    int*   bsum   = cursor + NNODES;
    int*   bbase  = bsum + NSB;
    float* ucm    = (float*)(bbase + NSB);         // [D2*NG]

    __hip_bfloat16* tbf = (__hip_bfloat16*)t;
    float* z2 = zin;   // overlay: zin dead after gemm1

    size_t zero_bytes = (size_t)(3 * NG * D + 1536) * 4 + (size_t)NNODES * 4;
    hipMemsetAsync(vn, 0, zero_bytes, stream);
    k_enc<<<NNODES / 4, 256, 0, stream>>>(x, Wenc, benc, eps, hin, hbf, zin);
    k_hist<<<(NEDGES + 255) / 256, 256, 0, stream>>>(ei, deg);
    k_scansum<<<NSB, 256, 0, stream>>>(deg, bsum);
    k_scanbase<<<1, 256, 0, stream>>>(bsum, bbase);
    k_scanwrite<<<NSB, 256, 0, stream>>>(deg, bbase, cursor);
    k_scatter<<<(NEDGES + 255) / 256, 256, 0, stream>>>(ei, ea, cursor, e32);

    for (int l = 0; l < 3; ++l) {
        float* statsA = stats + l * 256;
        float* statsB = stats + 768 + l * 128;
        if (l < 2) {
            float* vtb = (l == 0) ? vt0 : vt1;
            k_vt<<<(NNODES / 64 + 4) / 4, 256, 0, stream>>>(hin, batch, vtb);
            k_agg<<<NEDGES / (EPW * 4), 256, 0, stream>>>(e32, We, be, l, hbf, zin);
            k_vn1<<<32, 256, 0, stream>>>(vtb, vn, Wv1, bv1, l, ucm);
            k_vn2<<<16, 256, 0, stream>>>(ucm, Wv2, bv2, l, vn);
        } else {
            k_agg<<<NEDGES / (EPW * 4), 256, 0, stream>>>(e32, We, be, l, hbf, zin);
        }
        k_gemm1<<<(NNODES + 127) / 128, 256, 0, stream>>>(zin, W1, b1, l, tbf, statsA);
        k_gemm2<<<(NNODES + 127) / 128, 256, 0, stream>>>(tbf, statsA, W2, b2, l, z2, statsB);
        if (l < 2) {
            k_bnprep<<<NNODES * D / 256, 256, 0, stream>>>(z2, statsB, vn, batch, eps,
                                                           l + 1, hin, hbf, zin);
        } else {
            k_finish_att_proj<<<NNODES / 4, 256, 0, stream>>>(z2, statsB, Wna, bna, Wea,
                                                              proj, out);
        }
    }
    k_edge_final<<<(NEDGES + 255) / 256, 256, 0, stream>>>(ei, proj, bea, out);
}